// Round 1
// baseline (53.237 us; speedup 1.0000x reference)
//
#include <hip/hip_runtime.h>

// NodeSepDropoutLayer: ROWS=65536, COLS=512, P=0.6, PNT=0.5, NSP=0.9, NCLASS=10
//
// Derivation (see analysis): split == cols-split == 256, so every row adds 256
// to nz while can==true; nz_final = 65536*256 = 16777216 < ntz = 20132659, so
// `can` holds for ALL rows and `reached` is always False. remaining_p is the
// compile-time constant 3355443/2^24 (exact in f32).
//
// Per row r:
//   take_t = (labels[r] in target_classes) && start_attack && (row_rand[r] <= 0.9f)
//   keep cols = take_t ? [256,512) : [0,256)
//   out = keep && (residual_rand > remaining_p) ? input * 2.5f : 0
//
// Layout: 1 float4 per thread, 128 float4 per row -> each 64-lane wave covers
// exactly half a row, so waves are uniformly keep or zero (no divergence), and
// zero-half waves skip the input/resid reads entirely (halves read traffic).

#define NSD_ROWS 65536
#define NSD_COLS 512

__global__ __launch_bounds__(256) void NodeSepDropoutLayer_72164040508019_kernel(
    const float* __restrict__ input,
    const int*   __restrict__ labels,
    const int*   __restrict__ tclass,
    const int*   __restrict__ start_attack,
    const float* __restrict__ row_rand,
    const float* __restrict__ resid_rand,
    float*       __restrict__ out)
{
    const float remaining_p = 3355443.0f / 16777216.0f;  // exact f32

    const int tc0 = tclass[0];
    const int tc1 = tclass[1];
    const bool attack = (start_attack[0] != 0);

    // float4 index over the whole matrix
    const unsigned idx = blockIdx.x * blockDim.x + threadIdx.x;  // < 8388608
    const int row = (int)(idx >> 7);        // 128 float4 per row
    const int c   = (int)(idx & 127) * 4;   // starting column

    const int lab = labels[row];
    const bool is_t   = (lab == tc0) | (lab == tc1);
    const bool take_t = is_t & attack & (row_rand[row] <= 0.9f);
    const bool keep   = take_t ? (c >= 256) : (c < 256);

    const long long e = ((long long)row << 9) + c;

    float4 o = make_float4(0.0f, 0.0f, 0.0f, 0.0f);
    if (keep) {
        const float4 in = *(const float4*)(input + e);
        const float4 rr = *(const float4*)(resid_rand + e);
        o.x = (rr.x > remaining_p) ? in.x * 2.5f : 0.0f;
        o.y = (rr.y > remaining_p) ? in.y * 2.5f : 0.0f;
        o.z = (rr.z > remaining_p) ? in.z * 2.5f : 0.0f;
        o.w = (rr.w > remaining_p) ? in.w * 2.5f : 0.0f;
    }
    *(float4*)(out + e) = o;
}

extern "C" void kernel_launch(void* const* d_in, const int* in_sizes, int n_in,
                              void* d_out, int out_size, void* d_ws, size_t ws_size,
                              hipStream_t stream) {
    const float* input        = (const float*)d_in[0];
    const int*   labels       = (const int*)d_in[1];
    const int*   tclass       = (const int*)d_in[2];
    const int*   start_attack = (const int*)d_in[3];
    const float* row_rand     = (const float*)d_in[4];
    const float* resid_rand   = (const float*)d_in[5];
    float*       out          = (float*)d_out;

    const int total_f4 = NSD_ROWS * (NSD_COLS / 4);   // 8388608
    const int block = 256;
    const int grid  = total_f4 / block;               // 32768

    NodeSepDropoutLayer_72164040508019_kernel<<<grid, block, 0, stream>>>(
        input, labels, tclass, start_attack, row_rand, resid_rand, out);
}

// Round 2
// 40.345 us; speedup vs baseline: 1.3195x; 1.3195x over previous
//
#include <hip/hip_runtime.h>

// NodeSepDropoutLayer: ROWS=65536, COLS=512, P=0.6, PNT=0.5, NSP=0.9, NCLASS=10
//
// Constant-folded reference (see R0 analysis): split == cols-split == 256 so
// nz_final = 65536*256 = 16777216 < ntz = 20132659 -> `reached` always False,
// every row is "can", remaining_p = 3355443/2^24 exactly.
//
// Per row r:
//   take_t = (labels[r] in target_classes) && start_attack && (row_rand[r] <= 0.9f)
//   keep cols = take_t ? [256,512) : [0,256)
//   out = keep && (residual_rand > remaining_p) ? input * 2.5f : 0
//
// R1 -> R2 change: nontemporal float4 stores for `out`. The 128 MiB write
// stream is never re-read; keeping it out of L2/L3 leaves the 256 MiB
// Infinity Cache to hold the 128 MiB read working set (input keep-half +
// resid keep-half), which is re-read every graph replay.

#define NSD_ROWS 65536
#define NSD_COLS 512

typedef float f32x4 __attribute__((ext_vector_type(4)));

__global__ __launch_bounds__(256) void NodeSepDropoutLayer_72164040508019_kernel(
    const float* __restrict__ input,
    const int*   __restrict__ labels,
    const int*   __restrict__ tclass,
    const int*   __restrict__ start_attack,
    const float* __restrict__ row_rand,
    const float* __restrict__ resid_rand,
    float*       __restrict__ out)
{
    const float remaining_p = 3355443.0f / 16777216.0f;  // exact f32

    const int tc0 = tclass[0];
    const int tc1 = tclass[1];
    const bool attack = (start_attack[0] != 0);

    // float4 index over the whole matrix; 128 float4 per row -> each 64-lane
    // wave covers exactly half a row (wave-uniform keep/zero, no divergence).
    const unsigned idx = blockIdx.x * blockDim.x + threadIdx.x;  // < 8388608
    const int row = (int)(idx >> 7);
    const int c   = (int)(idx & 127) * 4;

    const int lab = labels[row];
    const bool is_t   = (lab == tc0) | (lab == tc1);
    const bool take_t = is_t & attack & (row_rand[row] <= 0.9f);
    const bool keep   = take_t ? (c >= 256) : (c < 256);

    const long long e = ((long long)row << 9) + c;

    f32x4 o = (f32x4)(0.0f);
    if (keep) {
        const f32x4 in = *(const f32x4*)(input + e);
        const f32x4 rr = *(const f32x4*)(resid_rand + e);
        o.x = (rr.x > remaining_p) ? in.x * 2.5f : 0.0f;
        o.y = (rr.y > remaining_p) ? in.y * 2.5f : 0.0f;
        o.z = (rr.z > remaining_p) ? in.z * 2.5f : 0.0f;
        o.w = (rr.w > remaining_p) ? in.w * 2.5f : 0.0f;
    }
    __builtin_nontemporal_store(o, (f32x4*)(out + e));
}

extern "C" void kernel_launch(void* const* d_in, const int* in_sizes, int n_in,
                              void* d_out, int out_size, void* d_ws, size_t ws_size,
                              hipStream_t stream) {
    const float* input        = (const float*)d_in[0];
    const int*   labels       = (const int*)d_in[1];
    const int*   tclass       = (const int*)d_in[2];
    const int*   start_attack = (const int*)d_in[3];
    const float* row_rand     = (const float*)d_in[4];
    const float* resid_rand   = (const float*)d_in[5];
    float*       out          = (float*)d_out;

    const int total_f4 = NSD_ROWS * (NSD_COLS / 4);   // 8388608
    const int block = 256;
    const int grid  = total_f4 / block;               // 32768

    NodeSepDropoutLayer_72164040508019_kernel<<<grid, block, 0, stream>>>(
        input, labels, tclass, start_attack, row_rand, resid_rand, out);
}